// Round 12
// baseline (181.304 us; speedup 1.0000x reference)
//
#include <hip/hip_runtime.h>
#include <hip/hip_bf16.h>

// Causal MHA forward, bf16-MFMA flash attention, round 16.
// Q:[B,L,H,E] K:[B,S,H,E] V:[B,S,H,D] fp32 -> O:[B,L,H,D] fp32.
// B=2, L=S=2048, H=16, E=D=64, scale=0.125 folded into Q (log2 domain).
//
// Wall-time law from r4..r15: wall = max-steps(worst CU) x per-step time.
// Per-step: r11's 1-barrier/4-wave dbuf = 2.08us; any 2-barrier/8-wave
// lockstep = ~5us (r7/r15: block barriers couple groups with private LDS).
// r11 = 32 steps x 2.08 = 66.5us. Round 16 halves max-steps keeping the
// r11 step structure VERBATIM:
//  1. SPLIT-K ACROSS BLOCKS: 1024 blocks = (head, strip s in 0..15, half p).
//     Block p does tiles t=p mod 2 -> s+1 steps, max 16, halves exactly even.
//     Fixed-cap softmax is linear -> partials add; no cross-block sync:
//     p=0 writes raw partial to O, p=1 to WS, l's to WS; attn_reduce sums
//     and normalizes (separate dispatch = safe ordering, unlike r9).
//  2. Per-CU slots {g+1,g+1,16-g,16-g}: worst CU = two 16-step blocks at
//     r11's exact residency. LDS padded to 40KB -> exactly 4 blocks/CU.
//  3. ws guard 17.3MB; else verified r11 fallback (zero-risk experiment).

#define NEG_INF (-1e30f)
#define CAP   16.0f

typedef __attribute__((ext_vector_type(8)))  short    short8;
typedef __attribute__((ext_vector_type(16))) float    f32x16;
typedef __attribute__((ext_vector_type(4)))  unsigned u32x4;

#define P1_OFF 0                 // partial-1 O image, 4194304 floats
#define L0_OFF 4194304           // l of half 0, 65536 floats [bh][q]
#define L1_OFF 4259840           // l of half 1, 65536 floats
#define WS_FLOATS 4325376        // 17,301,504 bytes

static __device__ __forceinline__ unsigned pk2(float lo, float hi) {
    __hip_bfloat162 h = __float22bfloat162_rn(make_float2(lo, hi));
    return *reinterpret_cast<unsigned*>(&h);
}

// ============== main: r11 step structure, K-halves across blocks =============
__global__ __launch_bounds__(256, 4)
void attn_split(const float* __restrict__ Q, const float* __restrict__ K,
                const float* __restrict__ V, float* __restrict__ O,
                float* __restrict__ WS) {
    const int lid = blockIdx.x;          // 0..1023
    const int x   = lid & 7;             // XCD slot
    const int c   = (lid >> 3) & 31;     // CU within XCD
    const int k4  = lid >> 8;            // slot 0..3
    const int bh  = x * 4 + (c & 3);     // 4 heads clustered per XCD
    const int b   = bh >> 4;
    const int h   = bh & 15;
    const int g   = c >> 2;              // 0..7
    const int s   = (k4 & 2) ? (15 - g) : g;   // strip (128 q rows)
    const int p   = k4 & 1;              // K-half: tiles t == p (mod 2)
    const int q0  = s * 128;             // steps = s+1, max 16

    const int tid  = threadIdx.x;
    const int wave = tid >> 6;           // 0..3: q sub-tile of 32 rows
    const int lane = tid & 63;
    const int l31  = lane & 31;
    const int hh   = lane >> 5;
    const int qw   = q0 + wave * 32;
    const int qg   = qw + l31;

    __shared__ short Kt[2][4096];        // K tile [key][e], swizzled, dbuf
    __shared__ short Vt[2][4096];        // V tile [d][key], swizzled, dbuf
    __shared__ float padLds[2048];       // 8KB pad -> 40KB: exactly 4 blocks/CU

    const float sc = 0.125f * 1.44269504088896340736f;  // scale * log2(e)

    // ---- Q fragment (B-operand), pre-scaled (r11 verbatim) ----
    short8 qf[4];
    {
        const float* qp = Q + (((size_t)b * 2048 + qg) * 16 + h) * 64 + hh * 8;
#pragma unroll
        for (int e = 0; e < 4; ++e) {
            const float4* q4 = (const float4*)(qp + e * 16);
            float4 x0 = q4[0], x1 = q4[1];
            u32x4 w = { pk2(x0.x * sc, x0.y * sc), pk2(x0.z * sc, x0.w * sc),
                        pk2(x1.x * sc, x1.y * sc), pk2(x1.z * sc, x1.w * sc) };
            qf[e] = __builtin_bit_cast(short8, w);
        }
    }

    // ---- staging geometry (r11 verbatim) ----
    const int rr  = tid >> 2;
    const int c2  = tid & 3;
    const int kOff0 = rr * 64 + (((2 * c2)     ^ (rr & 7)) * 8);
    const int kOff1 = rr * 64 + (((2 * c2 + 1) ^ (rr & 7)) * 8);
    const int kp2 = (tid & 31) * 2;
    const int c8  = (tid >> 5) * 8;
    int vOff[8];
#pragma unroll
    for (int jj = 0; jj < 8; ++jj)
        vOff[jj] = (c8 + jj) * 64 + (((kp2 >> 3) ^ jj) * 8) + (kp2 & 7);

    const float* Kthr = K + (((size_t)b * 2048 + rr ) * 16 + h) * 64 + c2 * 16;
    const float* Vthr = V + (((size_t)b * 2048 + kp2) * 16 + h) * 64 + c8;

    float4 kr[4], va[2], vb2[2];

    auto load_tile = [&](int kt) {
        const float4* kg = (const float4*)(Kthr + (size_t)kt * (64 * 16 * 64));
        kr[0] = kg[0]; kr[1] = kg[1]; kr[2] = kg[2]; kr[3] = kg[3];
        const float* vp = Vthr + (size_t)kt * (64 * 16 * 64);
        va[0]  = ((const float4*)vp)[0]; va[1]  = ((const float4*)vp)[1];
        const float* vq = vp + 16 * 64;
        vb2[0] = ((const float4*)vq)[0]; vb2[1] = ((const float4*)vq)[1];
    };
    auto store_tile = [&](int bsel) {
        short* KtB = Kt[bsel];
        short* VtB = Vt[bsel];
        u32x4 w0 = { pk2(kr[0].x, kr[0].y), pk2(kr[0].z, kr[0].w),
                     pk2(kr[1].x, kr[1].y), pk2(kr[1].z, kr[1].w) };
        u32x4 w1 = { pk2(kr[2].x, kr[2].y), pk2(kr[2].z, kr[2].w),
                     pk2(kr[3].x, kr[3].y), pk2(kr[3].z, kr[3].w) };
        *(u32x4*)&KtB[kOff0] = w0;
        *(u32x4*)&KtB[kOff1] = w1;
        const float* a0 = (const float*)va;
        const float* b0 = (const float*)vb2;
#pragma unroll
        for (int jj = 0; jj < 8; ++jj)
            *(unsigned*)&VtB[vOff[jj]] = pk2(a0[jj], b0[jj]);
    };

    f32x16 Oa0 = {}, Oa1 = {};
    float l = 0.f;
    const int swz = l31 & 7;

    // tile sequence: it = 2t + p, t = 0..s
    load_tile(p);
    store_tile(0);
    if (s > 0) load_tile(2 + p);
    __syncthreads();

    for (int t = 0; t <= s; ++t) {
        const int cur = t & 1;
        if (t + 1 <= s) store_tile(cur ^ 1);
        if (t + 2 <= s) load_tile(2 * (t + 2) + p);
        const int it = 2 * t + p;

        if (it * 64 <= qw + 31) {        // wave-uniform causal activity
            const short* KtB = Kt[cur];
            const short* VtB = Vt[cur];

            f32x16 S0 = {}, S1 = {};
            __builtin_amdgcn_s_setprio(1);
#pragma unroll
            for (int e = 0; e < 4; ++e) {
                short8 a = *(const short8*)&KtB[l31 * 64 + (((e * 2 + hh) ^ swz) * 8)];
                S0 = __builtin_amdgcn_mfma_f32_32x32x16_bf16(a, qf[e], S0, 0, 0, 0);
            }
#pragma unroll
            for (int e = 0; e < 4; ++e) {
                short8 a = *(const short8*)&KtB[(32 + l31) * 64 + (((e * 2 + hh) ^ swz) * 8)];
                S1 = __builtin_amdgcn_mfma_f32_32x32x16_bf16(a, qf[e], S1, 0, 0, 0);
            }
            __builtin_amdgcn_s_setprio(0);

            if (it * 64 + 63 > qw) {     // diagonal masks
#pragma unroll
                for (int r = 0; r < 16; ++r) {
                    const int kloc = (r & 3) + 8 * (r >> 2) + 4 * hh;
                    if (it * 64 + kloc      > qg) S0[r] = NEG_INF;
                    if (it * 64 + 32 + kloc > qg) S1[r] = NEG_INF;
                }
            }

            float ps = 0.f;
#pragma unroll
            for (int r = 0; r < 16; ++r) {
                S0[r] = exp2f(S0[r] - CAP); ps += S0[r];
                S1[r] = exp2f(S1[r] - CAP); ps += S1[r];
            }
            ps += __shfl_xor(ps, 32);
            l += ps;

            unsigned c0, c1, c2w, c3, c4, c5, c6, c7;
            c0 = pk2(S0[0],  S0[1]);  c1 = pk2(S0[2],  S0[3]);
            c2w = pk2(S0[4], S0[5]);  c3 = pk2(S0[6],  S0[7]);
            c4 = pk2(S0[8],  S0[9]);  c5 = pk2(S0[10], S0[11]);
            c6 = pk2(S0[12], S0[13]); c7 = pk2(S0[14], S0[15]);
            asm("v_permlane32_swap_b32 %0, %1" : "+v"(c0), "+v"(c2w));
            asm("v_permlane32_swap_b32 %0, %1" : "+v"(c1), "+v"(c3));
            asm("v_permlane32_swap_b32 %0, %1" : "+v"(c4), "+v"(c6));
            asm("v_permlane32_swap_b32 %0, %1" : "+v"(c5), "+v"(c7));
            u32x4 pwa = { c0, c1, c2w, c3 };
            u32x4 pwb = { c4, c5, c6, c7 };
            short8 pa00 = __builtin_bit_cast(short8, pwa);
            short8 pa01 = __builtin_bit_cast(short8, pwb);
            c0 = pk2(S1[0],  S1[1]);  c1 = pk2(S1[2],  S1[3]);
            c2w = pk2(S1[4], S1[5]);  c3 = pk2(S1[6],  S1[7]);
            c4 = pk2(S1[8],  S1[9]);  c5 = pk2(S1[10], S1[11]);
            c6 = pk2(S1[12], S1[13]); c7 = pk2(S1[14], S1[15]);
            asm("v_permlane32_swap_b32 %0, %1" : "+v"(c0), "+v"(c2w));
            asm("v_permlane32_swap_b32 %0, %1" : "+v"(c1), "+v"(c3));
            asm("v_permlane32_swap_b32 %0, %1" : "+v"(c4), "+v"(c6));
            asm("v_permlane32_swap_b32 %0, %1" : "+v"(c5), "+v"(c7));
            u32x4 pwc = { c0, c1, c2w, c3 };
            u32x4 pwd = { c4, c5, c6, c7 };
            short8 pa10 = __builtin_bit_cast(short8, pwc);
            short8 pa11 = __builtin_bit_cast(short8, pwd);

            __builtin_amdgcn_s_setprio(1);
            short8 v;
            v = *(const short8*)&VtB[l31 * 64 + (((0 + hh) ^ swz) * 8)];
            Oa0 = __builtin_amdgcn_mfma_f32_32x32x16_bf16(pa00, v, Oa0, 0, 0, 0);
            v = *(const short8*)&VtB[l31 * 64 + (((2 + hh) ^ swz) * 8)];
            Oa0 = __builtin_amdgcn_mfma_f32_32x32x16_bf16(pa01, v, Oa0, 0, 0, 0);
            v = *(const short8*)&VtB[l31 * 64 + (((4 + hh) ^ swz) * 8)];
            Oa0 = __builtin_amdgcn_mfma_f32_32x32x16_bf16(pa10, v, Oa0, 0, 0, 0);
            v = *(const short8*)&VtB[l31 * 64 + (((6 + hh) ^ swz) * 8)];
            Oa0 = __builtin_amdgcn_mfma_f32_32x32x16_bf16(pa11, v, Oa0, 0, 0, 0);
            v = *(const short8*)&VtB[(32 + l31) * 64 + (((0 + hh) ^ swz) * 8)];
            Oa1 = __builtin_amdgcn_mfma_f32_32x32x16_bf16(pa00, v, Oa1, 0, 0, 0);
            v = *(const short8*)&VtB[(32 + l31) * 64 + (((2 + hh) ^ swz) * 8)];
            Oa1 = __builtin_amdgcn_mfma_f32_32x32x16_bf16(pa01, v, Oa1, 0, 0, 0);
            v = *(const short8*)&VtB[(32 + l31) * 64 + (((4 + hh) ^ swz) * 8)];
            Oa1 = __builtin_amdgcn_mfma_f32_32x32x16_bf16(pa10, v, Oa1, 0, 0, 0);
            v = *(const short8*)&VtB[(32 + l31) * 64 + (((6 + hh) ^ swz) * 8)];
            Oa1 = __builtin_amdgcn_mfma_f32_32x32x16_bf16(pa11, v, Oa1, 0, 0, 0);
            __builtin_amdgcn_s_setprio(0);
        }
        __syncthreads();
    }

    if (l < 0.f) padLds[tid] = l;        // pad keep-alive (never true)

    // ---- epilogue: RAW partial -> (p? WS : O), l -> WS ----
    float* dstO = p ? (WS + P1_OFF) : O;
#pragma unroll
    for (int r = 0; r < 16; ++r) {
        const int rloc = (r & 3) + 8 * (r >> 2) + 4 * hh;
        float* op = dstO + (((size_t)b * 2048 + (qw + rloc)) * 16 + h) * 64;
        op[l31]      = Oa0[r];
        op[32 + l31] = Oa1[r];
    }
    float* Ld = WS + (p ? L1_OFF : L0_OFF);
    if (lane < 32) Ld[((b * 16 + h) << 11) + qw + l31] = l;
}

// ============== reduce: O = (O + P1) / (l0 + l1), coalesced =================
__global__ __launch_bounds__(256)
void attn_reduce(float* __restrict__ O, const float* __restrict__ WS) {
    const size_t i4 = (size_t)blockIdx.x * 256 + threadIdx.x;   // float4 idx
    const size_t i  = i4 * 4;
    const int b = (int)(i >> 21);
    const int q = (int)((i >> 10) & 2047);
    const int h = (int)((i >> 6) & 15);
    float4 a = ((float4*)O)[i4];
    const float4 c = ((const float4*)(WS + P1_OFF))[i4];
    const int lq = ((b * 16 + h) << 11) + q;
    const float inv = 1.0f / (WS[L0_OFF + lq] + WS[L1_OFF + lq]);
    a.x = (a.x + c.x) * inv;
    a.y = (a.y + c.y) * inv;
    a.z = (a.z + c.z) * inv;
    a.w = (a.w + c.w) * inv;
    ((float4*)O)[i4] = a;
}

// ================= fallback: round-11 kernel (verified, 66.5 us) =============
__global__ __launch_bounds__(256, 2)
void attn_fused_fb(const float* __restrict__ Q, const float* __restrict__ K,
                   const float* __restrict__ V, float* __restrict__ O) {
    const int lid = blockIdx.x;
    const int x   = lid & 7;
    const int c   = (lid >> 3) & 31;
    const int k2  = lid >> 8;
    const int bh  = x * 4 + (c & 3);
    const int b   = bh >> 4;
    const int h   = bh & 15;
    const int sp  = c >> 2;
    const int s   = k2 ? (15 - sp) : sp;
    const int q0  = s * 128;
    const int ntiles = 2 * s + 2;

    const int tid  = threadIdx.x;
    const int wave = tid >> 6;
    const int lane = tid & 63;
    const int l31  = lane & 31;
    const int hh   = lane >> 5;
    const int qw   = q0 + wave * 32;
    const int qg   = qw + l31;

    __shared__ short Kt[2][4096];
    __shared__ short Vt[2][4096];
    __shared__ float padLds[6144];

    const float sc = 0.125f * 1.44269504088896340736f;

    short8 qf[4];
    {
        const float* qp = Q + (((size_t)b * 2048 + qg) * 16 + h) * 64 + hh * 8;
#pragma unroll
        for (int e = 0; e < 4; ++e) {
            const float4* q4 = (const float4*)(qp + e * 16);
            float4 x0 = q4[0], x1 = q4[1];
            u32x4 w = { pk2(x0.x * sc, x0.y * sc), pk2(x0.z * sc, x0.w * sc),
                        pk2(x1.x * sc, x1.y * sc), pk2(x1.z * sc, x1.w * sc) };
            qf[e] = __builtin_bit_cast(short8, w);
        }
    }

    const int rr  = tid >> 2;
    const int c2  = tid & 3;
    const int kOff0 = rr * 64 + (((2 * c2)     ^ (rr & 7)) * 8);
    const int kOff1 = rr * 64 + (((2 * c2 + 1) ^ (rr & 7)) * 8);
    const int kp2 = (tid & 31) * 2;
    const int c8  = (tid >> 5) * 8;
    int vOff[8];
#pragma unroll
    for (int jj = 0; jj < 8; ++jj)
        vOff[jj] = (c8 + jj) * 64 + (((kp2 >> 3) ^ jj) * 8) + (kp2 & 7);

    const float* Kthr = K + (((size_t)b * 2048 + rr ) * 16 + h) * 64 + c2 * 16;
    const float* Vthr = V + (((size_t)b * 2048 + kp2) * 16 + h) * 64 + c8;

    float4 kr[4], va[2], vb2[2];

    auto load_tile = [&](int kt) {
        const float4* kg = (const float4*)(Kthr + (size_t)kt * (64 * 16 * 64));
        kr[0] = kg[0]; kr[1] = kg[1]; kr[2] = kg[2]; kr[3] = kg[3];
        const float* vp = Vthr + (size_t)kt * (64 * 16 * 64);
        va[0]  = ((const float4*)vp)[0]; va[1]  = ((const float4*)vp)[1];
        const float* vq = vp + 16 * 64;
        vb2[0] = ((const float4*)vq)[0]; vb2[1] = ((const float4*)vq)[1];
    };
    auto store_tile = [&](int bsel) {
        short* KtB = Kt[bsel];
        short* VtB = Vt[bsel];
        u32x4 w0 = { pk2(kr[0].x, kr[0].y), pk2(kr[0].z, kr[0].w),
                     pk2(kr[1].x, kr[1].y), pk2(kr[1].z, kr[1].w) };
        u32x4 w1 = { pk2(kr[2].x, kr[2].y), pk2(kr[2].z, kr[2].w),
                     pk2(kr[3].x, kr[3].y), pk2(kr[3].z, kr[3].w) };
        *(u32x4*)&KtB[kOff0] = w0;
        *(u32x4*)&KtB[kOff1] = w1;
        const float* a0 = (const float*)va;
        const float* b0 = (const float*)vb2;
#pragma unroll
        for (int jj = 0; jj < 8; ++jj)
            *(unsigned*)&VtB[vOff[jj]] = pk2(a0[jj], b0[jj]);
    };

    f32x16 Oa0 = {}, Oa1 = {};
    float l = 0.f;
    const int swz = l31 & 7;

    load_tile(0);
    store_tile(0);
    if (ntiles > 1) load_tile(1);
    __syncthreads();

    for (int kt = 0; kt < ntiles; ++kt) {
        const int cur = kt & 1;
        if (kt + 1 < ntiles) store_tile(cur ^ 1);
        if (kt + 2 < ntiles) load_tile(kt + 2);

        if (kt * 64 <= qw + 31) {
            const short* KtB = Kt[cur];
            const short* VtB = Vt[cur];

            f32x16 S0 = {}, S1 = {};
            __builtin_amdgcn_s_setprio(1);
#pragma unroll
            for (int e = 0; e < 4; ++e) {
                short8 a = *(const short8*)&KtB[l31 * 64 + (((e * 2 + hh) ^ swz) * 8)];
                S0 = __builtin_amdgcn_mfma_f32_32x32x16_bf16(a, qf[e], S0, 0, 0, 0);
            }
#pragma unroll
            for (int e = 0; e < 4; ++e) {
                short8 a = *(const short8*)&KtB[(32 + l31) * 64 + (((e * 2 + hh) ^ swz) * 8)];
                S1 = __builtin_amdgcn_mfma_f32_32x32x16_bf16(a, qf[e], S1, 0, 0, 0);
            }
            __builtin_amdgcn_s_setprio(0);

            if (kt * 64 + 63 > qw) {
#pragma unroll
                for (int r = 0; r < 16; ++r) {
                    const int kloc = (r & 3) + 8 * (r >> 2) + 4 * hh;
                    if (kt * 64 + kloc      > qg) S0[r] = NEG_INF;
                    if (kt * 64 + 32 + kloc > qg) S1[r] = NEG_INF;
                }
            }

            float ps = 0.f;
#pragma unroll
            for (int r = 0; r < 16; ++r) {
                S0[r] = exp2f(S0[r] - CAP); ps += S0[r];
                S1[r] = exp2f(S1[r] - CAP); ps += S1[r];
            }
            ps += __shfl_xor(ps, 32);
            l += ps;

            unsigned c0, c1, c2w, c3, c4, c5, c6, c7;
            c0 = pk2(S0[0],  S0[1]);  c1 = pk2(S0[2],  S0[3]);
            c2w = pk2(S0[4], S0[5]);  c3 = pk2(S0[6],  S0[7]);
            c4 = pk2(S0[8],  S0[9]);  c5 = pk2(S0[10], S0[11]);
            c6 = pk2(S0[12], S0[13]); c7 = pk2(S0[14], S0[15]);
            asm("v_permlane32_swap_b32 %0, %1" : "+v"(c0), "+v"(c2w));
            asm("v_permlane32_swap_b32 %0, %1" : "+v"(c1), "+v"(c3));
            asm("v_permlane32_swap_b32 %0, %1" : "+v"(c4), "+v"(c6));
            asm("v_permlane32_swap_b32 %0, %1" : "+v"(c5), "+v"(c7));
            u32x4 pwa = { c0, c1, c2w, c3 };
            u32x4 pwb = { c4, c5, c6, c7 };
            short8 pa00 = __builtin_bit_cast(short8, pwa);
            short8 pa01 = __builtin_bit_cast(short8, pwb);
            c0 = pk2(S1[0],  S1[1]);  c1 = pk2(S1[2],  S1[3]);
            c2w = pk2(S1[4], S1[5]);  c3 = pk2(S1[6],  S1[7]);
            c4 = pk2(S1[8],  S1[9]);  c5 = pk2(S1[10], S1[11]);
            c6 = pk2(S1[12], S1[13]); c7 = pk2(S1[14], S1[15]);
            asm("v_permlane32_swap_b32 %0, %1" : "+v"(c0), "+v"(c2w));
            asm("v_permlane32_swap_b32 %0, %1" : "+v"(c1), "+v"(c3));
            asm("v_permlane32_swap_b32 %0, %1" : "+v"(c4), "+v"(c6));
            asm("v_permlane32_swap_b32 %0, %1" : "+v"(c5), "+v"(c7));
            u32x4 pwc = { c0, c1, c2w, c3 };
            u32x4 pwd = { c4, c5, c6, c7 };
            short8 pa10 = __builtin_bit_cast(short8, pwc);
            short8 pa11 = __builtin_bit_cast(short8, pwd);

            __builtin_amdgcn_s_setprio(1);
            short8 v;
            v = *(const short8*)&VtB[l31 * 64 + (((0 + hh) ^ swz) * 8)];
            Oa0 = __builtin_amdgcn_mfma_f32_32x32x16_bf16(pa00, v, Oa0, 0, 0, 0);
            v = *(const short8*)&VtB[l31 * 64 + (((2 + hh) ^ swz) * 8)];
            Oa0 = __builtin_amdgcn_mfma_f32_32x32x16_bf16(pa01, v, Oa0, 0, 0, 0);
            v = *(const short8*)&VtB[l31 * 64 + (((4 + hh) ^ swz) * 8)];
            Oa0 = __builtin_amdgcn_mfma_f32_32x32x16_bf16(pa10, v, Oa0, 0, 0, 0);
            v = *(const short8*)&VtB[l31 * 64 + (((6 + hh) ^ swz) * 8)];
            Oa0 = __builtin_amdgcn_mfma_f32_32x32x16_bf16(pa11, v, Oa0, 0, 0, 0);
            v = *(const short8*)&VtB[(32 + l31) * 64 + (((0 + hh) ^ swz) * 8)];
            Oa1 = __builtin_amdgcn_mfma_f32_32x32x16_bf16(pa00, v, Oa1, 0, 0, 0);
            v = *(const short8*)&VtB[(32 + l31) * 64 + (((2 + hh) ^ swz) * 8)];
            Oa1 = __builtin_amdgcn_mfma_f32_32x32x16_bf16(pa01, v, Oa1, 0, 0, 0);
            v = *(const short8*)&VtB[(32 + l31) * 64 + (((4 + hh) ^ swz) * 8)];
            Oa1 = __builtin_amdgcn_mfma_f32_32x32x16_bf16(pa10, v, Oa1, 0, 0, 0);
            v = *(const short8*)&VtB[(32 + l31) * 64 + (((6 + hh) ^ swz) * 8)];
            Oa1 = __builtin_amdgcn_mfma_f32_32x32x16_bf16(pa11, v, Oa1, 0, 0, 0);
            __builtin_amdgcn_s_setprio(0);
        }
        __syncthreads();
    }

    if (l < 0.f) padLds[tid] = l;

    const float inv = 1.0f / l;
#pragma unroll
    for (int r = 0; r < 16; ++r) {
        const int rloc = (r & 3) + 8 * (r >> 2) + 4 * hh;
        const float ir = __shfl(inv, rloc);
        float* op = O + (((size_t)b * 2048 + (qw + rloc)) * 16 + h) * 64;
        op[l31]      = Oa0[r] * ir;
        op[32 + l31] = Oa1[r] * ir;
    }
}

extern "C" void kernel_launch(void* const* d_in, const int* in_sizes, int n_in,
                              void* d_out, int out_size, void* d_ws, size_t ws_size,
                              hipStream_t stream) {
    const float* Q = (const float*)d_in[0];
    const float* K = (const float*)d_in[1];
    const float* V = (const float*)d_in[2];
    float* O = (float*)d_out;
    if (d_ws && ws_size >= (size_t)WS_FLOATS * 4) {
        attn_split<<<dim3(1024), 256, 0, stream>>>(Q, K, V, O, (float*)d_ws);
        attn_reduce<<<dim3(4096), 256, 0, stream>>>(O, (const float*)d_ws);
    } else {
        attn_fused_fb<<<dim3(512), 256, 0, stream>>>(Q, K, V, O);
    }
}